// Round 4
// baseline (258.054 us; speedup 1.0000x reference)
//
#include <hip/hip_runtime.h>

// ts_zscore: rolling-window z-score
//   x: (B=64, T=4096, F=128) f32 ; out: (B=64, NK=4067, F=128) f32
//   out[b,k,f] = (x[b,k+29,f] - mean(x[b,k:k+30,f])) / (std(...) + 1e-4)
//
// R4: manual software pipeline. R3 was latency-bound (occ 38%, BW 34%, VALU 30%,
// VGPR=32 -> compiler never hoisted loads across iterations). Explicit register
// double-buffer: batch of 8 steps computes while the next batch's 16 loads are
// in flight. All array indices compile-time (rule #20).

#define B_DIM   64
#define T_DIM   4096
#define F_DIM   128
#define W_WIN   30
#define NK      4067      // T - W + 1 (stride 1, T-w included)
#define CH      64        // output rows per wave-chunk
#define CPB     64        // chunks per batch = ceil(NK/CH)
#define BATCH   8
#define EPS_Z   1e-4f

__global__ __launch_bounds__(256)
void ts_zscore_kernel(const float* __restrict__ x, float* __restrict__ out) {
    // bijective XCD swizzle: 1024 blocks, 8 XCDs, 128 contiguous blocks per XCD
    int bid = (int)blockIdx.x;
    int cpx = (int)gridDim.x >> 3;            // 1024/8 = 128
    int swz = (bid & 7) * cpx + (bid >> 3);   // adjacent chunks -> same XCD (halo L2 reuse)

    int wave = (int)threadIdx.x >> 6;
    int lane = (int)threadIdx.x & 63;         // each lane owns 2 features (float2)

    int g  = swz * 4 + wave;                  // global chunk id, 0..4095
    int b  = g >> 6;                          // / CPB
    int c  = g & (CPB - 1);
    int k0 = c * CH;
    int cnt = NK - k0; if (cnt > CH) cnt = CH;   // 64, or 35 for last chunk

    const float2* __restrict__ xp =
        (const float2*)(x + (size_t)b * T_DIM * F_DIM) + (size_t)k0 * 64 + lane;
    float2* __restrict__ op =
        (float2*)(out + (size_t)b * NK * F_DIM) + (size_t)k0 * 64 + lane;

    // warm-up: sums over rows k0 .. k0+28 (29 rows; independent loads)
    float s1x = 0.f, s1y = 0.f, s2x = 0.f, s2y = 0.f;
    #pragma unroll
    for (int i = 0; i < 29; ++i) {
        float2 v = xp[i * 64];
        s1x += v.x;       s1y += v.y;
        s2x += v.x * v.x; s2y += v.y * v.y;
    }

    const float inv_w = 1.0f / (float)W_WIN;

    // prime pipeline: batch 0 loads (row index clamped -> never OOB)
    float2 vb[BATCH], ob[BATCH];
    #pragma unroll
    for (int u = 0; u < BATCH; ++u) {
        int r = (u < cnt) ? u : (cnt - 1);
        vb[u] = xp[(29 + r) * 64];
        ob[u] = xp[r * 64];
    }

    for (int s0 = 0; s0 < cnt; s0 += BATCH) {
        // issue next batch's loads BEFORE the compute chain (the pipeline)
        float2 vn[BATCH], on[BATCH];
        #pragma unroll
        for (int u = 0; u < BATCH; ++u) {
            int ss = s0 + BATCH + u;
            int r  = (ss < cnt) ? ss : (cnt - 1);   // clamp: redundant but in-bounds
            vn[u] = xp[(29 + r) * 64];
            on[u] = xp[r * 64];
        }

        // compute current batch from registers
        #pragma unroll
        for (int u = 0; u < BATCH; ++u) {
            int ss = s0 + u;
            float2 v = vb[u], o = ob[u];

            float t1x = s1x + v.x,        t1y = s1y + v.y;
            float t2x = s2x + v.x * v.x,  t2y = s2y + v.y * v.y;

            float mx = t1x * inv_w,  my = t1y * inv_w;
            float vx = fmaxf(t2x * inv_w - mx * mx, 0.f);
            float vy = fmaxf(t2y * inv_w - my * my, 0.f);
            float ox = (v.x - mx) / (sqrtf(vx) + EPS_Z);
            float oy = (v.y - my) / (sqrtf(vy) + EPS_Z);
            if (ss < cnt) op[ss * 64] = make_float2(ox, oy);   // wave-uniform guard

            s1x = t1x - o.x;         s1y = t1y - o.y;
            s2x = t2x - o.x * o.x;   s2y = t2y - o.y * o.y;
        }

        // rotate buffers (forces the vmcnt wait here, after compute)
        #pragma unroll
        for (int u = 0; u < BATCH; ++u) { vb[u] = vn[u]; ob[u] = on[u]; }
    }
}

extern "C" void kernel_launch(void* const* d_in, const int* in_sizes, int n_in,
                              void* d_out, int out_size, void* d_ws, size_t ws_size,
                              hipStream_t stream) {
    const float* x = (const float*)d_in[0];
    float* out = (float*)d_out;
    dim3 grid((B_DIM * CPB) / 4);   // 1024 blocks of 4 waves, one chunk per wave
    dim3 block(256);
    ts_zscore_kernel<<<grid, block, 0, stream>>>(x, out);
}